// Round 1
// baseline (1126.080 us; speedup 1.0000x reference)
//
#include <hip/hip_runtime.h>
#include <hip/hip_bf16.h>
#include <math.h>

#define SEQ    2048
#define HIDDEN 2048
#define INTER  8192
#define NHEADS 16
#define KVH    8
#define HD     128

typedef __bf16 bf16x8 __attribute__((ext_vector_type(8)));
typedef __bf16 bf16x4 __attribute__((ext_vector_type(4)));
typedef float  f32x4  __attribute__((ext_vector_type(4)));

typedef __attribute__((address_space(1))) void* as1v;
typedef __attribute__((address_space(3))) void* as3v;

__device__ __forceinline__ void g2l16(const void* g, void* l) {
    __builtin_amdgcn_global_load_lds((as1v)g, (as3v)l, 16, 0, 0);
}

// ---------------------------------------------------------------------------
// RMSNorm (fp32 in) -> bf16 out.  One block per row of 2048.
// ---------------------------------------------------------------------------
__global__ __launch_bounds__(256) void k_rmsnorm(const float* __restrict__ x,
                                                 const float* __restrict__ w,
                                                 __bf16* __restrict__ out) {
    int row = blockIdx.x;
    int t   = threadIdx.x;
    const float4* xr = (const float4*)(x + (size_t)row * HIDDEN);
    float4 a = xr[t];
    float4 b = xr[t + 256];
    float ss = a.x*a.x + a.y*a.y + a.z*a.z + a.w*a.w
             + b.x*b.x + b.y*b.y + b.z*b.z + b.w*b.w;
#pragma unroll
    for (int d = 32; d > 0; d >>= 1) ss += __shfl_xor(ss, d);
    __shared__ float red[4];
    if ((t & 63) == 0) red[t >> 6] = ss;
    __syncthreads();
    float tot = red[0] + red[1] + red[2] + red[3];
    float r = rsqrtf(tot * (1.0f / (float)HIDDEN) + 1e-6f);
    const float4* wr = (const float4*)w;
    float4 wa = wr[t], wb = wr[t + 256];
    __bf16* o = out + (size_t)row * HIDDEN;
    bf16x4 pa, pb;
    pa[0] = (__bf16)(a.x * r * wa.x);
    pa[1] = (__bf16)(a.y * r * wa.y);
    pa[2] = (__bf16)(a.z * r * wa.z);
    pa[3] = (__bf16)(a.w * r * wa.w);
    pb[0] = (__bf16)(b.x * r * wb.x);
    pb[1] = (__bf16)(b.y * r * wb.y);
    pb[2] = (__bf16)(b.z * r * wb.z);
    pb[3] = (__bf16)(b.w * r * wb.w);
    *(bf16x4*)(o + 4*t)        = pa;
    *(bf16x4*)(o + 4*t + 1024) = pb;
}

// ---------------------------------------------------------------------------
// Shared GEMM core: C[128x128] tile, A bf16 [M,K], B fp32 [N,K] (NT).
// A staged bf16 via global_load_lds; B staged fp32 via global_load_lds with
// XOR-swizzled 16B columns (c16' = c16 ^ (row&7)) to balance LDS banks,
// converted to bf16 at fragment load.  4 waves, each owns a 64x64 subtile.
// ---------------------------------------------------------------------------
__device__ __forceinline__ void gemm_core(const __bf16* __restrict__ A, int lda,
                                          const float*  __restrict__ B, int ldb,
                                          int K, int m0, int n0,
                                          __bf16* As, float* Bs,
                                          f32x4 acc[4][4]) {
    int tid  = threadIdx.x;
    int wave = tid >> 6;
    int lane = tid & 63;
    int quad = lane >> 4;
    int l15  = lane & 15;
    int wm = wave >> 1, wn = wave & 1;

    // A staging: 8KB tile, 8 chunks of 1KB (16 rows); wave w -> chunks 2w,2w+1
    int arow  = wave*32 + (lane >> 2);
    int acol  = (lane & 3) * 8;
    char* aldst0 = (char*)As + wave*2048 + lane*16;
    char* aldst1 = aldst0 + 1024;

    for (int k0 = 0; k0 < K; k0 += 32) {
        __syncthreads();
        g2l16(A + (size_t)(m0 + arow)      * lda + k0 + acol, aldst0);
        g2l16(A + (size_t)(m0 + arow + 16) * lda + k0 + acol, aldst1);
#pragma unroll
        for (int t2 = 0; t2 < 4; ++t2) {
            int c   = wave*4 + t2;
            int row = c*8 + (lane >> 3);
            int cg  = ((lane & 7) ^ (row & 7)) * 4;   // swizzled global 16B col
            g2l16(B + (size_t)(n0 + row) * ldb + k0 + cg,
                  (char*)Bs + c*1024 + lane*16);
        }
        __syncthreads();

        bf16x8 af[4];
#pragma unroll
        for (int mt = 0; mt < 4; ++mt)
            af[mt] = *(const bf16x8*)((const char*)As +
                        (wm*64 + mt*16 + l15)*64 + quad*16);
        bf16x8 bfr[4];
#pragma unroll
        for (int nt = 0; nt < 4; ++nt) {
            int r = wn*64 + nt*16 + l15;
            const char* base = (const char*)Bs + r*128;
            int c0 = ((quad << 1) ^ (r & 7));
            f32x4 b0 = *(const f32x4*)(base + c0*16);
            f32x4 b1 = *(const f32x4*)(base + (c0 ^ 1)*16);
            bf16x8 bb;
            bb[0] = (__bf16)b0[0]; bb[1] = (__bf16)b0[1];
            bb[2] = (__bf16)b0[2]; bb[3] = (__bf16)b0[3];
            bb[4] = (__bf16)b1[0]; bb[5] = (__bf16)b1[1];
            bb[6] = (__bf16)b1[2]; bb[7] = (__bf16)b1[3];
            bfr[nt] = bb;
        }
#pragma unroll
        for (int mt = 0; mt < 4; ++mt)
#pragma unroll
            for (int nt = 0; nt < 4; ++nt)
                acc[mt][nt] = __builtin_amdgcn_mfma_f32_16x16x32_bf16(
                                  af[mt], bfr[nt], acc[mt][nt], 0, 0, 0);
    }
}

__device__ __forceinline__ void zero_acc(f32x4 acc[4][4]) {
#pragma unroll
    for (int i = 0; i < 4; ++i)
#pragma unroll
        for (int j = 0; j < 4; ++j) {
            acc[i][j][0] = 0.f; acc[i][j][1] = 0.f;
            acc[i][j][2] = 0.f; acc[i][j][3] = 0.f;
        }
}

// ---------------------------------------------------------------------------
// Fused QKV GEMM.  grid.x = 32 n-tiles: [0,16)=Q, [16,24)=K, [24,32)=V.
// ---------------------------------------------------------------------------
__global__ __launch_bounds__(256) void k_gemm_qkv(
        const __bf16* __restrict__ x,
        const float* __restrict__ wq, const float* __restrict__ wk,
        const float* __restrict__ wv,
        float* __restrict__ qf, float* __restrict__ kf, float* __restrict__ vf) {
    __shared__ __bf16 As[128*32];
    __shared__ float  Bs[128*32];
    int bn = blockIdx.x;
    const float* B; float* C; int ldc; int n0;
    if (bn < 16)      { B = wq; C = qf; ldc = 2048; n0 = bn*128; }
    else if (bn < 24) { B = wk; C = kf; ldc = 1024; n0 = (bn-16)*128; }
    else              { B = wv; C = vf; ldc = 1024; n0 = (bn-24)*128; }
    int m0 = blockIdx.y * 128;
    f32x4 acc[4][4]; zero_acc(acc);
    gemm_core(x, HIDDEN, B, HIDDEN, HIDDEN, m0, n0, As, Bs, acc);
    int lane = threadIdx.x & 63, wave = threadIdx.x >> 6;
    int quad = lane >> 4, l15 = lane & 15, wm = wave >> 1, wn = wave & 1;
#pragma unroll
    for (int mt = 0; mt < 4; ++mt)
#pragma unroll
        for (int nt = 0; nt < 4; ++nt)
#pragma unroll
            for (int r = 0; r < 4; ++r) {
                int gm = m0 + wm*64 + mt*16 + quad*4 + r;
                int gn = n0 + wn*64 + nt*16 + l15;
                C[(size_t)gm*ldc + gn] = acc[mt][nt][r];
            }
}

// ---------------------------------------------------------------------------
// O-projection + residual: h = resid + o @ wo^T  (fp32 out)
// ---------------------------------------------------------------------------
__global__ __launch_bounds__(256) void k_gemm_oproj(
        const __bf16* __restrict__ ob, const float* __restrict__ wo,
        const float* __restrict__ resid, float* __restrict__ h) {
    __shared__ __bf16 As[128*32];
    __shared__ float  Bs[128*32];
    int n0 = blockIdx.x * 128, m0 = blockIdx.y * 128;
    f32x4 acc[4][4]; zero_acc(acc);
    gemm_core(ob, HIDDEN, wo, HIDDEN, HIDDEN, m0, n0, As, Bs, acc);
    int lane = threadIdx.x & 63, wave = threadIdx.x >> 6;
    int quad = lane >> 4, l15 = lane & 15, wm = wave >> 1, wn = wave & 1;
#pragma unroll
    for (int mt = 0; mt < 4; ++mt)
#pragma unroll
        for (int nt = 0; nt < 4; ++nt)
#pragma unroll
            for (int r = 0; r < 4; ++r) {
                int gm = m0 + wm*64 + mt*16 + quad*4 + r;
                int gn = n0 + wn*64 + nt*16 + l15;
                size_t idx = (size_t)gm*HIDDEN + gn;
                h[idx] = acc[mt][nt][r] + resid[idx];
            }
}

// ---------------------------------------------------------------------------
// Gate+Up dual GEMM with fused SiLU: act = silu(y@wg^T) * (y@wu^T), bf16 out
// ---------------------------------------------------------------------------
__global__ __launch_bounds__(256) void k_gemm_gateup(
        const __bf16* __restrict__ y, const float* __restrict__ wg,
        const float* __restrict__ wu, __bf16* __restrict__ act) {
    __shared__ __bf16 As[128*32];
    __shared__ float  Bs[128*32];
    int n0 = blockIdx.x * 128, m0 = blockIdx.y * 128;
    f32x4 ag[4][4]; zero_acc(ag);
    f32x4 au[4][4]; zero_acc(au);
    gemm_core(y, HIDDEN, wg, HIDDEN, HIDDEN, m0, n0, As, Bs, ag);
    gemm_core(y, HIDDEN, wu, HIDDEN, HIDDEN, m0, n0, As, Bs, au);
    int lane = threadIdx.x & 63, wave = threadIdx.x >> 6;
    int quad = lane >> 4, l15 = lane & 15, wm = wave >> 1, wn = wave & 1;
#pragma unroll
    for (int mt = 0; mt < 4; ++mt)
#pragma unroll
        for (int nt = 0; nt < 4; ++nt)
#pragma unroll
            for (int r = 0; r < 4; ++r) {
                int gm = m0 + wm*64 + mt*16 + quad*4 + r;
                int gn = n0 + wn*64 + nt*16 + l15;
                float g = ag[mt][nt][r];
                float u = au[mt][nt][r];
                float s = g / (1.0f + __expf(-g));
                act[(size_t)gm*INTER + gn] = (__bf16)(s * u);
            }
}

// ---------------------------------------------------------------------------
// Down GEMM + residual: out = h + act @ wd^T  (fp32 out), K = 8192
// ---------------------------------------------------------------------------
__global__ __launch_bounds__(256) void k_gemm_down(
        const __bf16* __restrict__ act, const float* __restrict__ wd,
        const float* __restrict__ h, float* __restrict__ out) {
    __shared__ __bf16 As[128*32];
    __shared__ float  Bs[128*32];
    int n0 = blockIdx.x * 128, m0 = blockIdx.y * 128;
    f32x4 acc[4][4]; zero_acc(acc);
    gemm_core(act, INTER, wd, INTER, INTER, m0, n0, As, Bs, acc);
    int lane = threadIdx.x & 63, wave = threadIdx.x >> 6;
    int quad = lane >> 4, l15 = lane & 15, wm = wave >> 1, wn = wave & 1;
#pragma unroll
    for (int mt = 0; mt < 4; ++mt)
#pragma unroll
        for (int nt = 0; nt < 4; ++nt)
#pragma unroll
            for (int r = 0; r < 4; ++r) {
                int gm = m0 + wm*64 + mt*16 + quad*4 + r;
                int gn = n0 + wn*64 + nt*16 + l15;
                size_t idx = (size_t)gm*HIDDEN + gn;
                out[idx] = acc[mt][nt][r] + h[idx];
            }
}

// ---------------------------------------------------------------------------
// RoPE + bf16 cast.  One block per position.  Q gets softmax scale folded in.
// ---------------------------------------------------------------------------
__global__ __launch_bounds__(256) void k_rope(
        const float* __restrict__ qf, const float* __restrict__ kf,
        const int* __restrict__ pos_ids,
        __bf16* __restrict__ qb, __bf16* __restrict__ kb) {
    int p = blockIdx.x;
    float pos = (float)pos_ids[p];
    int t = threadIdx.x;
    const float LN1E4_64 = 0.14391156831212787f;  // ln(10000)/64
    const float QSCALE   = 0.08838834764831845f;  // 128^-0.5
#pragma unroll
    for (int it = 0; it < 8; ++it) {
        int f = it*256 + t;
        int d = f & 127;
        int i = d & 63;
        float ang = pos * expf(-LN1E4_64 * (float)i);
        float c = cosf(ang), s = sinf(ang);
        float x0 = qf[(size_t)p*2048 + f];
        float xr = (d < 64) ? -qf[(size_t)p*2048 + f + 64]
                            :  qf[(size_t)p*2048 + f - 64];
        qb[(size_t)p*2048 + f] = (__bf16)((x0*c + xr*s) * QSCALE);
    }
#pragma unroll
    for (int it = 0; it < 4; ++it) {
        int f = it*256 + t;
        int d = f & 127;
        int i = d & 63;
        float ang = pos * expf(-LN1E4_64 * (float)i);
        float c = cosf(ang), s = sinf(ang);
        float x0 = kf[(size_t)p*1024 + f];
        float xr = (d < 64) ? -kf[(size_t)p*1024 + f + 64]
                            :  kf[(size_t)p*1024 + f - 64];
        kb[(size_t)p*1024 + f] = (__bf16)(x0*c + xr*s);
    }
}

// ---------------------------------------------------------------------------
// V transpose + cast: vf [2048 pos][1024 f] fp32 -> vt [1024 f][2048 pos] bf16
// ---------------------------------------------------------------------------
__global__ __launch_bounds__(256) void k_transpose_v(
        const float* __restrict__ vf, __bf16* __restrict__ vt) {
    __shared__ __bf16 tile[64][65];
    int p0 = blockIdx.x * 64, f0 = blockIdx.y * 64;
    int t = threadIdx.x;
    int j = t & 63, i0 = t >> 6;
#pragma unroll
    for (int it = 0; it < 16; ++it) {
        int i = i0 + it*4;
        tile[i][j] = (__bf16)vf[(size_t)(p0 + i)*1024 + f0 + j];
    }
    __syncthreads();
#pragma unroll
    for (int it = 0; it < 16; ++it) {
        int jj = i0 + it*4;
        vt[(size_t)(f0 + jj)*2048 + p0 + j] = tile[j][jj];
    }
}

// ---------------------------------------------------------------------------
// Flash attention with same-sid + causal mask (window >= seq, always true).
// Block = (q-tile of 64, head).  4 waves, each owns 16 q rows.
// K tile [64 key][128 d], V^T tile [128 d][64 key] staged in LDS.
// ---------------------------------------------------------------------------
__global__ __launch_bounds__(256) void k_attn(
        const __bf16* __restrict__ qb,   // [2048,2048] rope'd, pre-scaled
        const __bf16* __restrict__ kb,   // [2048,1024] rope'd
        const __bf16* __restrict__ vt,   // [1024][2048] transposed
        const int* __restrict__ sid,     // [2048]
        __bf16* __restrict__ o) {        // [2048,2048]
    __shared__ int    sid_lds[SEQ];        // 8KB
    __shared__ __bf16 Kt[64*128];          // 16KB [key][d]
    __shared__ __bf16 Vt[128*64];          // 16KB [d][key]
    __shared__ __bf16 Pl[4*1024];          // 8KB, per-wave 16x64

    int qt = blockIdx.x;          // 0..31
    int h  = blockIdx.y;          // 0..15
    int hk = h >> 1;              // GQA: rep=2
    int tid = threadIdx.x, wave = tid >> 6, lane = tid & 63;
    int quad = lane >> 4, l15 = lane & 15;
    int q0 = qt * 64;
    int qrow_base = q0 + wave * 16;

    for (int i = tid; i < SEQ; i += 256) sid_lds[i] = sid[i];

    // Q fragments (A-operand: m = l15, k = seg*32 + quad*8 + j)
    bf16x8 qfrag[4];
#pragma unroll
    for (int seg = 0; seg < 4; ++seg)
        qfrag[seg] = *(const bf16x8*)(qb + (size_t)(qrow_base + l15)*2048
                                         + h*128 + seg*32 + quad*8);
    __syncthreads();
    int sq[4];
#pragma unroll
    for (int r = 0; r < 4; ++r) sq[r] = sid_lds[qrow_base + quad*4 + r];

    float m_i[4], l_i[4];
    f32x4 oacc[8];
#pragma unroll
    for (int r = 0; r < 4; ++r) { m_i[r] = -INFINITY; l_i[r] = 0.f; }
#pragma unroll
    for (int n = 0; n < 8; ++n) {
        oacc[n][0] = 0.f; oacc[n][1] = 0.f; oacc[n][2] = 0.f; oacc[n][3] = 0.f;
    }

    for (int kt = 0; kt <= qt; ++kt) {
        int k0 = kt * 64;
        __syncthreads();
        // stage K tile: 16 chunks of 1KB (4 rows of 256B each)
#pragma unroll
        for (int t2 = 0; t2 < 4; ++t2) {
            int c   = wave*4 + t2;
            int row = c*4 + (lane >> 4);
            g2l16(kb + (size_t)(k0 + row)*1024 + hk*128 + (lane & 15)*8,
                  (char*)Kt + c*1024 + lane*16);
        }
        // stage V^T tile: 16 chunks of 1KB (8 rows of 128B each)
#pragma unroll
        for (int t2 = 0; t2 < 4; ++t2) {
            int c   = wave*4 + t2;
            int row = c*8 + (lane >> 3);
            g2l16(vt + (size_t)(hk*128 + row)*2048 + k0 + (lane & 7)*8,
                  (char*)Vt + c*1024 + lane*16);
        }
        __syncthreads();

        // S = Q K^T  (16 q x 64 k per wave)
        f32x4 sacc[4];
#pragma unroll
        for (int nt = 0; nt < 4; ++nt) {
            sacc[nt][0]=0.f; sacc[nt][1]=0.f; sacc[nt][2]=0.f; sacc[nt][3]=0.f;
        }
#pragma unroll
        for (int seg = 0; seg < 4; ++seg)
#pragma unroll
            for (int nt = 0; nt < 4; ++nt) {
                bf16x8 kfr = *(const bf16x8*)((const char*)Kt +
                               (nt*16 + l15)*256 + seg*64 + quad*16);
                sacc[nt] = __builtin_amdgcn_mfma_f32_16x16x32_bf16(
                               qfrag[seg], kfr, sacc[nt], 0, 0, 0);
            }

        // mask + online softmax
        int sk[4], kg[4];
#pragma unroll
        for (int nt = 0; nt < 4; ++nt) {
            kg[nt] = k0 + nt*16 + l15;
            sk[nt] = sid_lds[kg[nt]];
        }
        float p[4][4];   // [nt][r]
#pragma unroll
        for (int r = 0; r < 4; ++r) {
            int qg = qrow_base + quad*4 + r;
            float mx = -INFINITY;
#pragma unroll
            for (int nt = 0; nt < 4; ++nt) {
                bool valid = (kg[nt] <= qg) && (sk[nt] == sq[r]);
                float s = valid ? sacc[nt][r] : -INFINITY;
                p[nt][r] = s;
                mx = fmaxf(mx, s);
            }
            mx = fmaxf(mx, __shfl_xor(mx, 1));
            mx = fmaxf(mx, __shfl_xor(mx, 2));
            mx = fmaxf(mx, __shfl_xor(mx, 4));
            mx = fmaxf(mx, __shfl_xor(mx, 8));
            float mn = fmaxf(m_i[r], mx);
            float alpha = (mn == m_i[r]) ? 1.0f : __expf(m_i[r] - mn);
            float rs = 0.f;
#pragma unroll
            for (int nt = 0; nt < 4; ++nt) {
                float pv = (p[nt][r] == -INFINITY) ? 0.f : __expf(p[nt][r] - mn);
                p[nt][r] = pv;
                rs += pv;
            }
            rs += __shfl_xor(rs, 1);
            rs += __shfl_xor(rs, 2);
            rs += __shfl_xor(rs, 4);
            rs += __shfl_xor(rs, 8);
            l_i[r] = l_i[r] * alpha + rs;
            m_i[r] = mn;
#pragma unroll
            for (int n = 0; n < 8; ++n) oacc[n][r] *= alpha;
        }

        // P (C/D layout) -> LDS -> A-operand layout
#pragma unroll
        for (int nt = 0; nt < 4; ++nt)
#pragma unroll
            for (int r = 0; r < 4; ++r)
                Pl[wave*1024 + (quad*4 + r)*64 + nt*16 + l15] = (__bf16)p[nt][r];
        __syncthreads();

        // O += P V
#pragma unroll
        for (int kc = 0; kc < 2; ++kc) {
            bf16x8 pfrag = *(const bf16x8*)((const char*)Pl + wave*2048 +
                             l15*128 + kc*64 + quad*16);
#pragma unroll
            for (int n = 0; n < 8; ++n) {
                bf16x8 vfr = *(const bf16x8*)((const char*)Vt +
                               (n*16 + l15)*128 + kc*64 + quad*16);
                oacc[n] = __builtin_amdgcn_mfma_f32_16x16x32_bf16(
                              pfrag, vfr, oacc[n], 0, 0, 0);
            }
        }
    }

    // epilogue: O /= l, write bf16
#pragma unroll
    for (int r = 0; r < 4; ++r) {
        float inv = 1.0f / l_i[r];
        size_t base = (size_t)(qrow_base + quad*4 + r)*2048 + h*128 + l15;
#pragma unroll
        for (int n = 0; n < 8; ++n)
            o[base + n*16] = (__bf16)(oacc[n][r] * inv);
    }
}

// ---------------------------------------------------------------------------
// Orchestration
// ---------------------------------------------------------------------------
extern "C" void kernel_launch(void* const* d_in, const int* in_sizes, int n_in,
                              void* d_out, int out_size, void* d_ws, size_t ws_size,
                              hipStream_t stream) {
    (void)in_sizes; (void)n_in; (void)out_size; (void)ws_size;
    const float* hidden = (const float*)d_in[0];
    const int*   sid    = (const int*)d_in[1];
    const int*   pos    = (const int*)d_in[2];
    const float* ln1    = (const float*)d_in[3];
    const float* wq     = (const float*)d_in[4];
    const float* wk     = (const float*)d_in[5];
    const float* wv     = (const float*)d_in[6];
    const float* wo     = (const float*)d_in[7];
    const float* ln2    = (const float*)d_in[8];
    const float* wg     = (const float*)d_in[9];
    const float* wu     = (const float*)d_in[10];
    const float* wd     = (const float*)d_in[11];
    float* out = (float*)d_out;
    char*  ws  = (char*)d_ws;

    // workspace layout (120 MB total)
    __bf16* xb   = (__bf16*)(ws + (0UL  << 20));   // [2048,2048] bf16   8MB
    float*  qf   = (float*) (ws + (8UL  << 20));   // [2048,2048] f32   16MB
    float*  kf   = (float*) (ws + (24UL << 20));   // [2048,1024] f32    8MB
    float*  vf   = (float*) (ws + (32UL << 20));   // [2048,1024] f32    8MB
    __bf16* qb   = (__bf16*)(ws + (40UL << 20));   // [2048,2048] bf16   8MB
    __bf16* kb   = (__bf16*)(ws + (48UL << 20));   // [2048,1024] bf16   4MB
    __bf16* vtb  = (__bf16*)(ws + (52UL << 20));   // [1024,2048] bf16   4MB
    __bf16* ob   = (__bf16*)(ws + (56UL << 20));   // [2048,2048] bf16   8MB
    float*  hbuf = (float*) (ws + (64UL << 20));   // [2048,2048] f32   16MB
    __bf16* yb   = (__bf16*)(ws + (80UL << 20));   // [2048,2048] bf16   8MB
    __bf16* actb = (__bf16*)(ws + (88UL << 20));   // [2048,8192] bf16  32MB

    k_rmsnorm<<<SEQ, 256, 0, stream>>>(hidden, ln1, xb);
    k_gemm_qkv<<<dim3(32, 16), 256, 0, stream>>>(xb, wq, wk, wv, qf, kf, vf);
    k_rope<<<SEQ, 256, 0, stream>>>(qf, kf, pos, qb, kb);
    k_transpose_v<<<dim3(32, 16), 256, 0, stream>>>(vf, vtb);
    k_attn<<<dim3(32, 16), 256, 0, stream>>>(qb, kb, vtb, sid, ob);
    k_gemm_oproj<<<dim3(16, 16), 256, 0, stream>>>(ob, wo, hidden, hbuf);
    k_rmsnorm<<<SEQ, 256, 0, stream>>>(hbuf, ln2, yb);
    k_gemm_gateup<<<dim3(64, 16), 256, 0, stream>>>(yb, wg, wu, actb);
    k_gemm_down<<<dim3(16, 16), 256, 0, stream>>>(actb, wd, hbuf, out);
}

// Round 2
// 859.723 us; speedup vs baseline: 1.3098x; 1.3098x over previous
//
#include <hip/hip_runtime.h>
#include <hip/hip_bf16.h>
#include <math.h>

#define SEQ    2048
#define HIDDEN 2048
#define INTER  8192
#define NHEADS 16
#define KVH    8
#define HD     128

typedef __bf16 bf16x8 __attribute__((ext_vector_type(8)));
typedef __bf16 bf16x4 __attribute__((ext_vector_type(4)));
typedef float  f32x4  __attribute__((ext_vector_type(4)));

typedef __attribute__((address_space(1))) void* as1v;
typedef __attribute__((address_space(3))) void* as3v;

__device__ __forceinline__ void g2l16(const void* g, void* l) {
    __builtin_amdgcn_global_load_lds((as1v)g, (as3v)l, 16, 0, 0);
}

// weight blob layout (elements) inside ws: wq, wk, wv, wo, wg, wu, wd
#define OFF_WQ 0UL
#define OFF_WK 4194304UL
#define OFF_WV 6291456UL
#define OFF_WO 8388608UL
#define OFF_WG 12582912UL
#define OFF_WU 29360128UL
#define OFF_WD 46137344UL
#define W_TOTAL 62914560UL

// ---------------------------------------------------------------------------
// Weight fp32 -> bf16 conversion (once per launch).  8 elems/thread.
// ---------------------------------------------------------------------------
__global__ __launch_bounds__(256) void k_cvt(
        const float* __restrict__ wq, const float* __restrict__ wk,
        const float* __restrict__ wv, const float* __restrict__ wo,
        const float* __restrict__ wg, const float* __restrict__ wu,
        const float* __restrict__ wd, __bf16* __restrict__ wb) {
    size_t e = ((size_t)blockIdx.x * 256 + threadIdx.x) * 8;
    const float* src; size_t base;
    if      (e < OFF_WK) { src = wq; base = OFF_WQ; }
    else if (e < OFF_WV) { src = wk; base = OFF_WK; }
    else if (e < OFF_WO) { src = wv; base = OFF_WV; }
    else if (e < OFF_WG) { src = wo; base = OFF_WO; }
    else if (e < OFF_WU) { src = wg; base = OFF_WG; }
    else if (e < OFF_WD) { src = wu; base = OFF_WU; }
    else                 { src = wd; base = OFF_WD; }
    const float4* s = (const float4*)(src + (e - base));
    float4 a = s[0], b = s[1];
    bf16x8 o;
    o[0] = (__bf16)a.x; o[1] = (__bf16)a.y; o[2] = (__bf16)a.z; o[3] = (__bf16)a.w;
    o[4] = (__bf16)b.x; o[5] = (__bf16)b.y; o[6] = (__bf16)b.z; o[7] = (__bf16)b.w;
    *(bf16x8*)(wb + e) = o;
}

// ---------------------------------------------------------------------------
// RMSNorm (fp32 in) -> bf16 out.  One block per row of 2048.
// ---------------------------------------------------------------------------
__global__ __launch_bounds__(256) void k_rmsnorm(const float* __restrict__ x,
                                                 const float* __restrict__ w,
                                                 __bf16* __restrict__ out) {
    int row = blockIdx.x;
    int t   = threadIdx.x;
    const float4* xr = (const float4*)(x + (size_t)row * HIDDEN);
    float4 a = xr[t];
    float4 b = xr[t + 256];
    float ss = a.x*a.x + a.y*a.y + a.z*a.z + a.w*a.w
             + b.x*b.x + b.y*b.y + b.z*b.z + b.w*b.w;
#pragma unroll
    for (int d = 32; d > 0; d >>= 1) ss += __shfl_xor(ss, d);
    __shared__ float red[4];
    if ((t & 63) == 0) red[t >> 6] = ss;
    __syncthreads();
    float tot = red[0] + red[1] + red[2] + red[3];
    float r = rsqrtf(tot * (1.0f / (float)HIDDEN) + 1e-6f);
    const float4* wr = (const float4*)w;
    float4 wa = wr[t], wb = wr[t + 256];
    __bf16* o = out + (size_t)row * HIDDEN;
    bf16x4 pa, pb;
    pa[0] = (__bf16)(a.x * r * wa.x);
    pa[1] = (__bf16)(a.y * r * wa.y);
    pa[2] = (__bf16)(a.z * r * wa.z);
    pa[3] = (__bf16)(a.w * r * wa.w);
    pb[0] = (__bf16)(b.x * r * wb.x);
    pb[1] = (__bf16)(b.y * r * wb.y);
    pb[2] = (__bf16)(b.z * r * wb.z);
    pb[3] = (__bf16)(b.w * r * wb.w);
    *(bf16x4*)(o + 4*t)        = pa;
    *(bf16x4*)(o + 4*t + 1024) = pb;
}

// ---------------------------------------------------------------------------
// Pure-bf16 GEMM core, m97 structure: C[128x128] tile, A [M,K] bf16,
// B [N,K] bf16, both staged via global_load_lds width=16.  4 waves.
// Wave n-columns: wn*32 + (nt&1)*16 + (nt>>1)*64  (so RoPE partner col^64
// is acc[mt][nt^2], in-register, for the fused qkv epilogue).
// ---------------------------------------------------------------------------
__device__ __forceinline__ int gncol(int wn, int nt, int l15) {
    return wn*32 + ((nt & 1) << 4) + ((nt >> 1) << 6) + l15;
}

__device__ __forceinline__ void gemm_core(const __bf16* __restrict__ A, int lda,
                                          const __bf16* __restrict__ B, int ldb,
                                          int K, int m0, int n0,
                                          __bf16* As, __bf16* Bs,
                                          f32x4 acc[4][4]) {
    int tid  = threadIdx.x;
    int wave = tid >> 6;
    int lane = tid & 63;
    int quad = lane >> 4;
    int l15  = lane & 15;
    int wm = wave >> 1, wn = wave & 1;

    int srow = wave*32 + (lane >> 2);
    int scol = (lane & 3) * 8;
    char* adst = (char*)As + wave*2048 + lane*16;
    char* bdst = (char*)Bs + wave*2048 + lane*16;

    for (int k0 = 0; k0 < K; k0 += 32) {
        __syncthreads();
        g2l16(A + (size_t)(m0 + srow)      * lda + k0 + scol, adst);
        g2l16(A + (size_t)(m0 + srow + 16) * lda + k0 + scol, adst + 1024);
        g2l16(B + (size_t)(n0 + srow)      * ldb + k0 + scol, bdst);
        g2l16(B + (size_t)(n0 + srow + 16) * ldb + k0 + scol, bdst + 1024);
        __syncthreads();

        bf16x8 af[4], bfr[4];
#pragma unroll
        for (int mt = 0; mt < 4; ++mt)
            af[mt] = *(const bf16x8*)((const char*)As +
                        (wm*64 + mt*16 + l15)*64 + quad*16);
#pragma unroll
        for (int nt = 0; nt < 4; ++nt) {
            int r = gncol(wn, nt, l15);
            bfr[nt] = *(const bf16x8*)((const char*)Bs + r*64 + quad*16);
        }
#pragma unroll
        for (int mt = 0; mt < 4; ++mt)
#pragma unroll
            for (int nt = 0; nt < 4; ++nt)
                acc[mt][nt] = __builtin_amdgcn_mfma_f32_16x16x32_bf16(
                                  af[mt], bfr[nt], acc[mt][nt], 0, 0, 0);
    }
}

__device__ __forceinline__ void zero_acc(f32x4 acc[4][4]) {
#pragma unroll
    for (int i = 0; i < 4; ++i)
#pragma unroll
        for (int j = 0; j < 4; ++j) {
            acc[i][j][0] = 0.f; acc[i][j][1] = 0.f;
            acc[i][j][2] = 0.f; acc[i][j][3] = 0.f;
        }
}

// ---------------------------------------------------------------------------
// Fused QKV GEMM + RoPE + V-transpose.
// grid.x = 32 n-tiles: [0,16)=Q, [16,24)=K, [24,32)=V.
// Q written pre-scaled by HD^-0.5.  V written transposed [feat][pos] bf16.
// ---------------------------------------------------------------------------
__global__ __launch_bounds__(256) void k_gemm_qkv(
        const __bf16* __restrict__ x, const __bf16* __restrict__ wb,
        const int* __restrict__ pos_ids,
        __bf16* __restrict__ qb, __bf16* __restrict__ kb,
        __bf16* __restrict__ vtb) {
    __shared__ __bf16 As[128*32];
    __shared__ __bf16 Bs[128*32];
    int bn = blockIdx.x;
    int m0 = blockIdx.y * 128;
    const __bf16* B; int n0; int kind;
    if (bn < 16)      { B = wb + OFF_WQ; n0 = bn*128;      kind = 0; }
    else if (bn < 24) { B = wb + OFF_WK; n0 = (bn-16)*128; kind = 1; }
    else              { B = wb + OFF_WV; n0 = (bn-24)*128; kind = 2; }
    f32x4 acc[4][4]; zero_acc(acc);
    gemm_core(x, HIDDEN, B, HIDDEN, HIDDEN, m0, n0, As, Bs, acc);

    int tid = threadIdx.x, wave = tid >> 6, lane = tid & 63;
    int quad = lane >> 4, l15 = lane & 15, wm = wave >> 1, wn = wave & 1;

    if (kind == 2) {
        // V: transposed store, bf16x4 down the pos dimension
#pragma unroll
        for (int mt = 0; mt < 4; ++mt)
#pragma unroll
            for (int nt = 0; nt < 4; ++nt) {
                int f  = n0 + gncol(wn, nt, l15);
                int gm = m0 + wm*64 + mt*16 + quad*4;
                bf16x4 vv;
                vv[0] = (__bf16)acc[mt][nt][0];
                vv[1] = (__bf16)acc[mt][nt][1];
                vv[2] = (__bf16)acc[mt][nt][2];
                vv[3] = (__bf16)acc[mt][nt][3];
                *(bf16x4*)(vtb + (size_t)f*2048 + gm) = vv;
            }
    } else {
        __bf16* out = (kind == 0) ? qb : kb;
        int ldc     = (kind == 0) ? 2048 : 1024;
        float scale = (kind == 0) ? 0.08838834764831845f : 1.0f;
        // RoPE: d = wn*32 + (nt&1)*16 + (nt>>1)*64 + l15; i = d & 63
        int i0 = wn*32 + l15;
        const float LN1E4_64 = 0.14391156831212787f;
        float f0 = __expf(-LN1E4_64 * (float)i0);
        float f1 = __expf(-LN1E4_64 * (float)(i0 + 16));
#pragma unroll
        for (int mt = 0; mt < 4; ++mt)
#pragma unroll
            for (int r = 0; r < 4; ++r) {
                int gm = m0 + wm*64 + mt*16 + quad*4 + r;
                float pos = (float)pos_ids[gm];
                float s0, c0, s1, c1;
                __sincosf(pos * f0, &s0, &c0);
                __sincosf(pos * f1, &s1, &c1);
                float a0 = acc[mt][0][r], a1 = acc[mt][1][r];
                float a2 = acc[mt][2][r], a3 = acc[mt][3][r];
                size_t rowb = (size_t)gm * ldc + n0 + wn*32 + l15;
                out[rowb]      = (__bf16)((a0*c0 - a2*s0) * scale);
                out[rowb + 16] = (__bf16)((a1*c1 - a3*s1) * scale);
                out[rowb + 64] = (__bf16)((a2*c0 + a0*s0) * scale);
                out[rowb + 80] = (__bf16)((a3*c1 + a1*s1) * scale);
            }
    }
}

// ---------------------------------------------------------------------------
// O-projection + residual: h = resid + o @ wo^T  (fp32 out)
// ---------------------------------------------------------------------------
__global__ __launch_bounds__(256) void k_gemm_oproj(
        const __bf16* __restrict__ ob, const __bf16* __restrict__ wo,
        const float* __restrict__ resid, float* __restrict__ h) {
    __shared__ __bf16 As[128*32];
    __shared__ __bf16 Bs[128*32];
    int n0 = blockIdx.x * 128, m0 = blockIdx.y * 128;
    f32x4 acc[4][4]; zero_acc(acc);
    gemm_core(ob, HIDDEN, wo, HIDDEN, HIDDEN, m0, n0, As, Bs, acc);
    int lane = threadIdx.x & 63, wave = threadIdx.x >> 6;
    int quad = lane >> 4, l15 = lane & 15, wm = wave >> 1, wn = wave & 1;
#pragma unroll
    for (int mt = 0; mt < 4; ++mt)
#pragma unroll
        for (int nt = 0; nt < 4; ++nt)
#pragma unroll
            for (int r = 0; r < 4; ++r) {
                int gm = m0 + wm*64 + mt*16 + quad*4 + r;
                int gn = n0 + gncol(wn, nt, l15);
                size_t idx = (size_t)gm*HIDDEN + gn;
                h[idx] = acc[mt][nt][r] + resid[idx];
            }
}

// ---------------------------------------------------------------------------
// Gate+Up dual GEMM with fused SiLU: act = silu(y@wg^T) * (y@wu^T), bf16 out
// ---------------------------------------------------------------------------
__global__ __launch_bounds__(256) void k_gemm_gateup(
        const __bf16* __restrict__ y, const __bf16* __restrict__ wg,
        const __bf16* __restrict__ wu, __bf16* __restrict__ act) {
    __shared__ __bf16 As[128*32];
    __shared__ __bf16 Bs[128*32];
    int n0 = blockIdx.x * 128, m0 = blockIdx.y * 128;
    f32x4 ag[4][4]; zero_acc(ag);
    f32x4 au[4][4]; zero_acc(au);
    gemm_core(y, HIDDEN, wg, HIDDEN, HIDDEN, m0, n0, As, Bs, ag);
    gemm_core(y, HIDDEN, wu, HIDDEN, HIDDEN, m0, n0, As, Bs, au);
    int lane = threadIdx.x & 63, wave = threadIdx.x >> 6;
    int quad = lane >> 4, l15 = lane & 15, wm = wave >> 1, wn = wave & 1;
#pragma unroll
    for (int mt = 0; mt < 4; ++mt)
#pragma unroll
        for (int nt = 0; nt < 4; ++nt)
#pragma unroll
            for (int r = 0; r < 4; ++r) {
                int gm = m0 + wm*64 + mt*16 + quad*4 + r;
                int gn = n0 + gncol(wn, nt, l15);
                float g = ag[mt][nt][r];
                float u = au[mt][nt][r];
                float s = g / (1.0f + __expf(-g));
                act[(size_t)gm*INTER + gn] = (__bf16)(s * u);
            }
}

// ---------------------------------------------------------------------------
// Down GEMM + residual: out = h + act @ wd^T  (fp32 out), K = 8192
// ---------------------------------------------------------------------------
__global__ __launch_bounds__(256) void k_gemm_down(
        const __bf16* __restrict__ act, const __bf16* __restrict__ wd,
        const float* __restrict__ h, float* __restrict__ out) {
    __shared__ __bf16 As[128*32];
    __shared__ __bf16 Bs[128*32];
    int n0 = blockIdx.x * 128, m0 = blockIdx.y * 128;
    f32x4 acc[4][4]; zero_acc(acc);
    gemm_core(act, INTER, wd, INTER, INTER, m0, n0, As, Bs, acc);
    int lane = threadIdx.x & 63, wave = threadIdx.x >> 6;
    int quad = lane >> 4, l15 = lane & 15, wm = wave >> 1, wn = wave & 1;
#pragma unroll
    for (int mt = 0; mt < 4; ++mt)
#pragma unroll
        for (int nt = 0; nt < 4; ++nt)
#pragma unroll
            for (int r = 0; r < 4; ++r) {
                int gm = m0 + wm*64 + mt*16 + quad*4 + r;
                int gn = n0 + gncol(wn, nt, l15);
                size_t idx = (size_t)gm*HIDDEN + gn;
                out[idx] = acc[mt][nt][r] + h[idx];
            }
}

// ---------------------------------------------------------------------------
// Flash attention with same-sid + causal mask (window >= seq, always true).
// Block = (q-tile of 64, head).  4 waves, each owns 16 q rows.
// ---------------------------------------------------------------------------
__global__ __launch_bounds__(256) void k_attn(
        const __bf16* __restrict__ qb,   // [2048,2048] rope'd, pre-scaled
        const __bf16* __restrict__ kb,   // [2048,1024] rope'd
        const __bf16* __restrict__ vt,   // [1024][2048] transposed
        const int* __restrict__ sid,     // [2048]
        __bf16* __restrict__ o) {        // [2048,2048]
    __shared__ int    sid_lds[SEQ];        // 8KB
    __shared__ __bf16 Kt[64*128];          // 16KB [key][d]
    __shared__ __bf16 Vt[128*64];          // 16KB [d][key]
    __shared__ __bf16 Pl[4*1024];          // 8KB, per-wave 16x64

    int qt = blockIdx.x;          // 0..31
    int h  = blockIdx.y;          // 0..15
    int hk = h >> 1;              // GQA: rep=2
    int tid = threadIdx.x, wave = tid >> 6, lane = tid & 63;
    int quad = lane >> 4, l15 = lane & 15;
    int q0 = qt * 64;
    int qrow_base = q0 + wave * 16;

    for (int i = tid; i < SEQ; i += 256) sid_lds[i] = sid[i];

    bf16x8 qfrag[4];
#pragma unroll
    for (int seg = 0; seg < 4; ++seg)
        qfrag[seg] = *(const bf16x8*)(qb + (size_t)(qrow_base + l15)*2048
                                         + h*128 + seg*32 + quad*8);
    __syncthreads();
    int sq[4];
#pragma unroll
    for (int r = 0; r < 4; ++r) sq[r] = sid_lds[qrow_base + quad*4 + r];

    float m_i[4], l_i[4];
    f32x4 oacc[8];
#pragma unroll
    for (int r = 0; r < 4; ++r) { m_i[r] = -INFINITY; l_i[r] = 0.f; }
#pragma unroll
    for (int n = 0; n < 8; ++n) {
        oacc[n][0] = 0.f; oacc[n][1] = 0.f; oacc[n][2] = 0.f; oacc[n][3] = 0.f;
    }

    for (int kt = 0; kt <= qt; ++kt) {
        int k0 = kt * 64;
        __syncthreads();
#pragma unroll
        for (int t2 = 0; t2 < 4; ++t2) {
            int c   = wave*4 + t2;
            int row = c*4 + (lane >> 4);
            g2l16(kb + (size_t)(k0 + row)*1024 + hk*128 + (lane & 15)*8,
                  (char*)Kt + c*1024 + lane*16);
        }
#pragma unroll
        for (int t2 = 0; t2 < 4; ++t2) {
            int c   = wave*4 + t2;
            int row = c*8 + (lane >> 3);
            g2l16(vt + (size_t)(hk*128 + row)*2048 + k0 + (lane & 7)*8,
                  (char*)Vt + c*1024 + lane*16);
        }
        __syncthreads();

        f32x4 sacc[4];
#pragma unroll
        for (int nt = 0; nt < 4; ++nt) {
            sacc[nt][0]=0.f; sacc[nt][1]=0.f; sacc[nt][2]=0.f; sacc[nt][3]=0.f;
        }
#pragma unroll
        for (int seg = 0; seg < 4; ++seg)
#pragma unroll
            for (int nt = 0; nt < 4; ++nt) {
                bf16x8 kfr = *(const bf16x8*)((const char*)Kt +
                               (nt*16 + l15)*256 + seg*64 + quad*16);
                sacc[nt] = __builtin_amdgcn_mfma_f32_16x16x32_bf16(
                               qfrag[seg], kfr, sacc[nt], 0, 0, 0);
            }

        int sk[4], kg[4];
#pragma unroll
        for (int nt = 0; nt < 4; ++nt) {
            kg[nt] = k0 + nt*16 + l15;
            sk[nt] = sid_lds[kg[nt]];
        }
        float p[4][4];
#pragma unroll
        for (int r = 0; r < 4; ++r) {
            int qg = qrow_base + quad*4 + r;
            float mx = -INFINITY;
#pragma unroll
            for (int nt = 0; nt < 4; ++nt) {
                bool valid = (kg[nt] <= qg) && (sk[nt] == sq[r]);
                float s = valid ? sacc[nt][r] : -INFINITY;
                p[nt][r] = s;
                mx = fmaxf(mx, s);
            }
            mx = fmaxf(mx, __shfl_xor(mx, 1));
            mx = fmaxf(mx, __shfl_xor(mx, 2));
            mx = fmaxf(mx, __shfl_xor(mx, 4));
            mx = fmaxf(mx, __shfl_xor(mx, 8));
            float mn = fmaxf(m_i[r], mx);
            float alpha = (mn == m_i[r]) ? 1.0f : __expf(m_i[r] - mn);
            float rs = 0.f;
#pragma unroll
            for (int nt = 0; nt < 4; ++nt) {
                float pv = (p[nt][r] == -INFINITY) ? 0.f : __expf(p[nt][r] - mn);
                p[nt][r] = pv;
                rs += pv;
            }
            rs += __shfl_xor(rs, 1);
            rs += __shfl_xor(rs, 2);
            rs += __shfl_xor(rs, 4);
            rs += __shfl_xor(rs, 8);
            l_i[r] = l_i[r] * alpha + rs;
            m_i[r] = mn;
#pragma unroll
            for (int n = 0; n < 8; ++n) oacc[n][r] *= alpha;
        }

#pragma unroll
        for (int nt = 0; nt < 4; ++nt)
#pragma unroll
            for (int r = 0; r < 4; ++r)
                Pl[wave*1024 + (quad*4 + r)*64 + nt*16 + l15] = (__bf16)p[nt][r];
        __syncthreads();

#pragma unroll
        for (int kc = 0; kc < 2; ++kc) {
            bf16x8 pfrag = *(const bf16x8*)((const char*)Pl + wave*2048 +
                             l15*128 + kc*64 + quad*16);
#pragma unroll
            for (int n = 0; n < 8; ++n) {
                bf16x8 vfr = *(const bf16x8*)((const char*)Vt +
                               (n*16 + l15)*128 + kc*64 + quad*16);
                oacc[n] = __builtin_amdgcn_mfma_f32_16x16x32_bf16(
                              pfrag, vfr, oacc[n], 0, 0, 0);
            }
        }
    }

#pragma unroll
    for (int r = 0; r < 4; ++r) {
        float inv = 1.0f / l_i[r];
        size_t base = (size_t)(qrow_base + quad*4 + r)*2048 + h*128 + l15;
#pragma unroll
        for (int n = 0; n < 8; ++n)
            o[base + n*16] = (__bf16)(oacc[n][r] * inv);
    }
}

// ---------------------------------------------------------------------------
// Orchestration
// ---------------------------------------------------------------------------
extern "C" void kernel_launch(void* const* d_in, const int* in_sizes, int n_in,
                              void* d_out, int out_size, void* d_ws, size_t ws_size,
                              hipStream_t stream) {
    (void)in_sizes; (void)n_in; (void)out_size; (void)ws_size;
    const float* hidden = (const float*)d_in[0];
    const int*   sid    = (const int*)d_in[1];
    const int*   pos    = (const int*)d_in[2];
    const float* ln1    = (const float*)d_in[3];
    const float* wq     = (const float*)d_in[4];
    const float* wk     = (const float*)d_in[5];
    const float* wv     = (const float*)d_in[6];
    const float* wo     = (const float*)d_in[7];
    const float* ln2    = (const float*)d_in[8];
    const float* wg     = (const float*)d_in[9];
    const float* wu     = (const float*)d_in[10];
    const float* wd     = (const float*)d_in[11];
    float* out = (float*)d_out;
    char*  ws  = (char*)d_ws;

    // workspace layout, 176 MB total (lifetimes overlapped):
    __bf16* wb   = (__bf16*)(ws);                  // 0..120MB  weights bf16
    __bf16* xb   = (__bf16*)(ws + (120UL << 20));  // 120..128  x (rms1), later ob, later yb
    __bf16* qb   = (__bf16*)(ws + (128UL << 20));  // 128..136  q
    __bf16* kb   = (__bf16*)(ws + (136UL << 20));  // 136..140  k
    __bf16* vtb  = (__bf16*)(ws + (140UL << 20));  // 140..144  v^T
    __bf16* ob   = (__bf16*)(ws + (120UL << 20));  // reuse xb after qkv
    float*  hbuf = (float*) (ws + (128UL << 20));  // 128..144  reuse q/k/v after attn
    __bf16* yb   = (__bf16*)(ws + (120UL << 20));  // reuse ob after oproj
    __bf16* actb = (__bf16*)(ws + (144UL << 20));  // 144..176

    k_cvt<<<30720, 256, 0, stream>>>(wq, wk, wv, wo, wg, wu, wd, wb);
    k_rmsnorm<<<SEQ, 256, 0, stream>>>(hidden, ln1, xb);
    k_gemm_qkv<<<dim3(32, 16), 256, 0, stream>>>(xb, wb, pos, qb, kb, vtb);
    k_attn<<<dim3(32, 16), 256, 0, stream>>>(qb, kb, vtb, sid, ob);
    k_gemm_oproj<<<dim3(16, 16), 256, 0, stream>>>(ob, wb + OFF_WO, hidden, hbuf);
    k_rmsnorm<<<SEQ, 256, 0, stream>>>(hbuf, ln2, yb);
    k_gemm_gateup<<<dim3(64, 16), 256, 0, stream>>>(yb, wb + OFF_WG, wb + OFF_WU, actb);
    k_gemm_down<<<dim3(16, 16), 256, 0, stream>>>(actb, wb + OFF_WD, hbuf, out);
}